// Round 8
// baseline (67.779 us; speedup 1.0000x reference)
//
#include <hip/hip_runtime.h>
#include <cmath>

// HistorySAGE: 3 GraphSAGE layers, only the 20000 live rows computed per layer
// (idx < 20000, output rows < 20000). Multi-launch (coop grid.sync measured
// 3.2x slower, round 4). Round 8: layer 2 restructured by linearity —
// mean(h1_nb)@W2 == mean(h1_nb@W2) — so we project h1 to 47 cols FIRST
// (dense, row-local) and gather 96B rows instead of 512B rows (5x fewer
// gather bytes; gather measured as the dominant term at ~7 TB/s random-row).
constexpr int ROWS = 20000;
constexpr int BM   = 32;             // rows per block tile for layers 0/1
constexpr int GRID = ROWS / BM;      // 625 blocks
constexpr float BN_EPS = 1e-5f;

using f32x4  = __attribute__((ext_vector_type(4))) float;
using short8 = __attribute__((ext_vector_type(8))) short;

__device__ __forceinline__ float bf2f(unsigned short u) {
    unsigned int x = ((unsigned int)u) << 16;
    return __builtin_bit_cast(float, x);
}
__device__ __forceinline__ unsigned short f2bf(float f) {
    unsigned int x = __builtin_bit_cast(unsigned int, f);
    unsigned int r = x + 0x7fffu + ((x >> 16) & 1u);   // RNE
    return (unsigned short)(r >> 16);
}

// Fragment-major weight layout: Bf[((n16*K32 + k32)*64 + lane)*8 + q] =
// bf16 of Wcat[k32*32 + (lane>>4)*8 + q][n16*16 + (lane&15)], Wcat = [W; R].
// A wave reading lane*8 shorts at a (n16,k32) block base gets its exact
// 16x16x32 MFMA B-fragment fully coalesced (1KB/wave).
__device__ __forceinline__ void convw_frag(const float* __restrict__ W, const float* __restrict__ R,
                                           unsigned short* __restrict__ B, int K, int Ntrue, int N16,
                                           int gtid, int gstride)
{
    const int K32 = 2 * K / 32;
    const int total = N16 * K32 * 64;
    for (int j = gtid; j < total; j += gstride) {
        const int lane = j & 63;
        const int rest = j >> 6;
        const int k32 = rest % K32, n16 = rest / K32;
        const int n  = n16 * 16 + (lane & 15);
        const int kb = k32 * 32 + (lane >> 4) * 8;
        short8 o;
        #pragma unroll
        for (int q = 0; q < 8; ++q) {
            const int kk = kb + q;
            float v = 0.f;
            if (n < Ntrue) v = (kk < K) ? W[(size_t)kk * Ntrue + n] : R[(size_t)(kk - K) * Ntrue + n];
            o[q] = (short)f2bf(v);
        }
        *(short8*)(B + (size_t)j * 8) = o;
    }
}

// Layer-2 projection weights, single-K frag layout (K=256, 6 col-tiles):
// n<47 -> W2[k][n]; 48<=n<95 -> R2[k][n-48]; else 0.
__device__ __forceinline__ void convw_proj2(const float* __restrict__ W, const float* __restrict__ R,
                                            unsigned short* __restrict__ B, int gtid, int gstride)
{
    constexpr int KS = 8;                 // 256/32
    const int total = 6 * KS * 64;
    for (int j = gtid; j < total; j += gstride) {
        const int lane = j & 63, rest = j >> 6;
        const int ks = rest % KS, t = rest / KS;
        const int n  = t * 16 + (lane & 15);
        const int kb = ks * 32 + (lane >> 4) * 8;
        short8 o;
        #pragma unroll
        for (int q = 0; q < 8; ++q) {
            const int kk = kb + q;
            float v = 0.f;
            if (n < 47)                 v = W[(size_t)kk * 47 + n];
            else if (n >= 48 && n < 95) v = R[(size_t)kk * 47 + (n - 48)];
            o[q] = (short)f2bf(v);
        }
        *(short8*)(B + (size_t)j * 8) = o;
    }
}

struct Args {
    const float* x; const int* ptr; const int* idx;
    const float *W0, *b0, *R0, *W1, *b1, *R1, *W2, *b2, *R2;
    const float *g0, *be0, *rm0, *rv0, *g1, *be1, *rm1, *rv1;
    unsigned short *B0, *B1, *Bp2, *xb, *h0, *h1, *y2w, *y2r;
    float* out;
};

// prep: x rows [0,ROWS) -> bf16 + all weight buffers.
__global__ __launch_bounds__(256) void prep(Args a)
{
    const int gtid = blockIdx.x * 256 + threadIdx.x, gstride = gridDim.x * 256;
    for (int i = gtid; i < ROWS * 16; i += gstride) {
        const int row = i >> 4, c = (i & 15) * 8;
        const float4 v0 = *(const float4*)(a.x + (size_t)row * 128 + c);
        const float4 v1 = *(const float4*)(a.x + (size_t)row * 128 + c + 4);
        short8 o;
        o[0]=(short)f2bf(v0.x); o[1]=(short)f2bf(v0.y); o[2]=(short)f2bf(v0.z); o[3]=(short)f2bf(v0.w);
        o[4]=(short)f2bf(v1.x); o[5]=(short)f2bf(v1.y); o[6]=(short)f2bf(v1.z); o[7]=(short)f2bf(v1.w);
        *(short8*)(a.xb + (size_t)row * 128 + c) = o;
    }
    convw_frag(a.W0, a.R0, a.B0, 128, 256, 16, gtid, gstride);
    convw_frag(a.W1, a.R1, a.B1, 256, 256, 16, gtid, gstride);
    convw_proj2(a.W2, a.R2, a.Bp2, gtid, gstride);
}

// ---- layer 0/1 phase helpers (proven round-7 structure) ----

template<int K>
__device__ __forceinline__ void gather_agg(const unsigned short* __restrict__ src,
    const int* __restrict__ idx, const int* sIdx, const int* sOff, const int* sCnt,
    const float* sInv, unsigned short* sA, int tid)
{
    constexpr int KA = K + 8, CA = K / 8;
    for (int u = tid; u < BM * CA; u += 256) {
        const int r = u / CA, c = (u - (u / CA) * CA) * 8;
        const int cnt = sCnt[r];
        float acc[8];
        #pragma unroll
        for (int q = 0; q < 8; ++q) acc[q] = 0.f;
        if (__builtin_expect(cnt == 10, 1)) {
            int nb[10];
            #pragma unroll
            for (int j = 0; j < 10; ++j) nb[j] = sIdx[r * 10 + j];
            short8 v[10];
            #pragma unroll
            for (int j = 0; j < 10; ++j) v[j] = *(const short8*)(src + (size_t)nb[j] * K + c);
            #pragma unroll
            for (int j = 0; j < 10; ++j)
                #pragma unroll
                for (int q = 0; q < 8; ++q) acc[q] += bf2f((unsigned short)v[j][q]);
        } else {
            for (int p = 0; p < cnt; ++p) {
                const int nb = idx[sOff[r] + p];
                const short8 v = *(const short8*)(src + (size_t)nb * K + c);
                #pragma unroll
                for (int q = 0; q < 8; ++q) acc[q] += bf2f((unsigned short)v[q]);
            }
        }
        const float inv = sInv[r];
        short8 o;
        #pragma unroll
        for (int q = 0; q < 8; ++q) o[q] = (short)f2bf(acc[q] * inv);
        *(short8*)(&sA[r * KA + c]) = o;
    }
}

template<int K>
__device__ __forceinline__ void self_gemm256(const unsigned short* __restrict__ src,
    const unsigned short* __restrict__ Bf, int rowBase, int lane, int wid, f32x4 (&acc)[2][4])
{
    constexpr int KS_A = K / 32, KS_T = 2 * K / 32;
    const int mrow = lane & 15, kg = (lane >> 4) * 8;
    const int nt0 = wid * 4;
    #pragma unroll
    for (int ks2 = 0; ks2 < KS_A; ++ks2) {
        const int kc = ks2 * 32 + kg;
        const short8 a0 = *(const short8*)(src + (size_t)(rowBase + mrow) * K + kc);
        const short8 a1 = *(const short8*)(src + (size_t)(rowBase + 16 + mrow) * K + kc);
        #pragma unroll
        for (int t = 0; t < 4; ++t) {
            const short8 b = *(const short8*)(Bf + ((size_t)(nt0 + t) * KS_T + KS_A + ks2) * 512 + lane * 8);
            acc[0][t] = __builtin_amdgcn_mfma_f32_16x16x32_bf16(a0, b, acc[0][t], 0, 0, 0);
            acc[1][t] = __builtin_amdgcn_mfma_f32_16x16x32_bf16(a1, b, acc[1][t], 0, 0, 0);
        }
    }
}

template<int K>
__device__ __forceinline__ void agg_gemm256(const unsigned short* sA,
    const unsigned short* __restrict__ Bf, int lane, int wid, f32x4 (&acc)[2][4])
{
    constexpr int KA = K + 8, KS_A = K / 32, KS_T = 2 * K / 32;
    const int mrow = lane & 15, kg = (lane >> 4) * 8;
    const int nt0 = wid * 4;
    #pragma unroll
    for (int ks = 0; ks < KS_A; ++ks) {
        const short8 a0 = *(const short8*)(&sA[mrow * KA + ks * 32 + kg]);
        const short8 a1 = *(const short8*)(&sA[(16 + mrow) * KA + ks * 32 + kg]);
        #pragma unroll
        for (int t = 0; t < 4; ++t) {
            const short8 b = *(const short8*)(Bf + ((size_t)(nt0 + t) * KS_T + ks) * 512 + lane * 8);
            acc[0][t] = __builtin_amdgcn_mfma_f32_16x16x32_bf16(a0, b, acc[0][t], 0, 0, 0);
            acc[1][t] = __builtin_amdgcn_mfma_f32_16x16x32_bf16(a1, b, acc[1][t], 0, 0, 0);
        }
    }
}

// 32 rows x 256 cols, BN+ReLU -> bf16, block-parity phase stagger.
template<int K>
__global__ __launch_bounds__(256, 3)
void layer_kernel(const unsigned short* __restrict__ src,
                  const int* __restrict__ ptr, const int* __restrict__ idx,
                  const unsigned short* __restrict__ Bf, const float* __restrict__ bias,
                  const float* __restrict__ gam, const float* __restrict__ bet,
                  const float* __restrict__ rmean, const float* __restrict__ rvar,
                  unsigned short* __restrict__ dstB)
{
    constexpr int KA = K + 8;
    __shared__ unsigned short sA[BM * KA];
    __shared__ int   sIdx[BM * 10];
    __shared__ int   sOff[BM];
    __shared__ int   sCnt[BM];
    __shared__ float sInv[BM];

    const int tid = threadIdx.x;
    const int rowBase = blockIdx.x * BM;
    const bool evenBlk = (blockIdx.x & 1) == 0;   // block-uniform

    if (tid < BM) {
        const int p0 = ptr[rowBase + tid], p1 = ptr[rowBase + tid + 1];
        sOff[tid] = p0; sCnt[tid] = p1 - p0; sInv[tid] = 1.0f / (float)(p1 - p0);
    }
    __syncthreads();
    for (int u = tid; u < BM * 10; u += 256) {
        const int r = u / 10, j = u - r * 10;
        sIdx[u] = (j < sCnt[r]) ? idx[sOff[r] + j] : 0;
    }
    __syncthreads();

    const int lane = tid & 63, wid = tid >> 6;

    f32x4 acc[2][4];
    #pragma unroll
    for (int i = 0; i < 2; ++i)
        #pragma unroll
        for (int t = 0; t < 4; ++t) acc[i][t] = (f32x4){0.f, 0.f, 0.f, 0.f};

    if (evenBlk) {
        self_gemm256<K>(src, Bf, rowBase, lane, wid, acc);
        gather_agg<K>(src, idx, sIdx, sOff, sCnt, sInv, sA, tid);
        __syncthreads();
        agg_gemm256<K>(sA, Bf, lane, wid, acc);
    } else {
        gather_agg<K>(src, idx, sIdx, sOff, sCnt, sInv, sA, tid);
        __syncthreads();
        self_gemm256<K>(src, Bf, rowBase, lane, wid, acc);
        agg_gemm256<K>(sA, Bf, lane, wid, acc);
    }

    const int nt0 = wid * 4, mrow = lane & 15;
    #pragma unroll
    for (int t = 0; t < 4; ++t) {
        const int col = (nt0 + t) * 16 + mrow;
        const float sc = gam[col] * rsqrtf(rvar[col] + BN_EPS);
        const float sh = bet[col] - rmean[col] * sc;
        const float bb = bias[col];
        #pragma unroll
        for (int i = 0; i < 2; ++i)
            #pragma unroll
            for (int reg = 0; reg < 4; ++reg) {
                const int row = rowBase + i * 16 + (lane >> 4) * 4 + reg;
                float h = acc[i][t][reg] + bb;
                h = fmaxf(h * sc + sh, 0.f);
                dstB[(size_t)row * 256 + col] = f2bf(h);
            }
    }
}

// proj2: y2w[r][c] = (h1[r] @ W2)[c], y2r[r][c] = (h1[r] @ R2)[c], bf16, no bias.
// Dense, row-local, no LDS, no barrier. 64 rows/block (4 waves x 16 rows).
__global__ __launch_bounds__(256, 4)
void proj2_kernel(const unsigned short* __restrict__ h1,
                  const unsigned short* __restrict__ Bf,
                  unsigned short* __restrict__ y2w,
                  unsigned short* __restrict__ y2r)
{
    constexpr int K = 256, KS = K / 32;
    const int tid = threadIdx.x, lane = tid & 63, wid = tid >> 6;
    const int rowBase = blockIdx.x * 64 + wid * 16;
    const int mrow = lane & 15, kg = (lane >> 4) * 8;
    const int arow0 = rowBase + mrow;
    const int arow = (arow0 < ROWS) ? arow0 : (ROWS - 1);   // clamp reads
    f32x4 acc[6];
    #pragma unroll
    for (int t = 0; t < 6; ++t) acc[t] = (f32x4){0.f, 0.f, 0.f, 0.f};
    #pragma unroll
    for (int ks = 0; ks < KS; ++ks) {
        const short8 aa = *(const short8*)(h1 + (size_t)arow * K + ks * 32 + kg);
        #pragma unroll
        for (int t = 0; t < 6; ++t) {
            const short8 b = *(const short8*)(Bf + ((size_t)t * KS + ks) * 512 + lane * 8);
            acc[t] = __builtin_amdgcn_mfma_f32_16x16x32_bf16(aa, b, acc[t], 0, 0, 0);
        }
    }
    #pragma unroll
    for (int t = 0; t < 6; ++t) {
        const int col = t * 16 + mrow;
        #pragma unroll
        for (int reg = 0; reg < 4; ++reg) {
            const int row = rowBase + (lane >> 4) * 4 + reg;
            if (row < ROWS) {
                const unsigned short v = f2bf(acc[t][reg]);
                if (col < 48) y2w[(size_t)row * 48 + col] = v;
                else          y2r[(size_t)row * 48 + (col - 48)] = v;
            }
        }
    }
}

// combine2: out[r] = log_softmax(mean_nb(y2w) + y2r[r] + b2). 16 rows/block,
// 16 lanes per row (cols c, c+16, c+32). Gathers 96B rows (vs 512B pre-split).
__global__ __launch_bounds__(256)
void combine2_kernel(const int* __restrict__ ptr, const int* __restrict__ idx,
                     const unsigned short* __restrict__ y2w,
                     const unsigned short* __restrict__ y2r,
                     const float* __restrict__ b2,
                     float* __restrict__ out)
{
    const int tid = threadIdx.x, lane = tid & 63, wid = tid >> 6;
    const int c = lane & 15, sub = lane >> 4;
    const int row = blockIdx.x * 16 + wid * 4 + sub;
    const int p0 = ptr[row], p1 = ptr[row + 1];
    const float inv = 1.0f / (float)(p1 - p0);
    float s0 = 0.f, s1 = 0.f, s2 = 0.f;
    for (int p = p0; p < p1; ++p) {
        const int nb = idx[p];
        const unsigned short* yr = y2w + (size_t)nb * 48;
        s0 += bf2f(yr[c]); s1 += bf2f(yr[16 + c]); s2 += bf2f(yr[32 + c]);
    }
    const unsigned short* sr = y2r + (size_t)row * 48;
    const bool ok2 = (32 + c) < 47;
    float v0 = s0 * inv + bf2f(sr[c])      + b2[c];
    float v1 = s1 * inv + bf2f(sr[16 + c]) + b2[16 + c];
    float v2 = ok2 ? (s2 * inv + bf2f(sr[32 + c]) + b2[32 + c]) : -3.0e38f;
    float mx = fmaxf(fmaxf(v0, v1), v2);
    #pragma unroll
    for (int o = 1; o < 16; o <<= 1) mx = fmaxf(mx, __shfl_xor(mx, o, 16));
    float s = expf(v0 - mx) + expf(v1 - mx) + (ok2 ? expf(v2 - mx) : 0.f);
    #pragma unroll
    for (int o = 1; o < 16; o <<= 1) s += __shfl_xor(s, o, 16);
    const float ls = mx + logf(s);
    out[(size_t)row * 47 + c]      = v0 - ls;
    out[(size_t)row * 47 + 16 + c] = v1 - ls;
    if (ok2) out[(size_t)row * 47 + 32 + c] = v2 - ls;
}

extern "C" void kernel_launch(void* const* d_in, const int* in_sizes, int n_in,
                              void* d_out, int out_size, void* d_ws, size_t ws_size,
                              hipStream_t stream)
{
    char* ws = (char*)d_ws;
    Args a;
    a.x   = (const float*)d_in[0];
    a.ptr = (const int*)d_in[1];
    a.idx = (const int*)d_in[2];
    a.W0  = (const float*)d_in[3];  a.b0 = (const float*)d_in[4];  a.R0 = (const float*)d_in[5];
    a.W1  = (const float*)d_in[6];  a.b1 = (const float*)d_in[7];  a.R1 = (const float*)d_in[8];
    a.W2  = (const float*)d_in[9];  a.b2 = (const float*)d_in[10]; a.R2 = (const float*)d_in[11];
    a.g0  = (const float*)d_in[12]; a.be0 = (const float*)d_in[13];
    a.rm0 = (const float*)d_in[14]; a.rv0 = (const float*)d_in[15];
    a.g1  = (const float*)d_in[16]; a.be1 = (const float*)d_in[17];
    a.rm1 = (const float*)d_in[18]; a.rv1 = (const float*)d_in[19];
    a.B0  = (unsigned short*)(ws);                        // 128 KB
    a.B1  = (unsigned short*)(ws + 131072);               // 256 KB
    a.Bp2 = (unsigned short*)(ws + 393216);               //  48 KB
    a.xb  = (unsigned short*)(ws + 442368);               // 20000*128 bf16 = 5.12 MB
    a.h0  = (unsigned short*)(ws + 5562368);              // 20000*256 bf16 = 10.24 MB
    a.h1  = (unsigned short*)(ws + 15802368);             // 20000*256 bf16
    a.y2w = (unsigned short*)(ws + 26042368);             // 20000*48 bf16 = 1.92 MB
    a.y2r = (unsigned short*)(ws + 27962368);             // 20000*48 bf16
    a.out = (float*)d_out;

    prep<<<1280, 256, 0, stream>>>(a);
    layer_kernel<128><<<GRID, 256, 0, stream>>>(a.xb, a.ptr, a.idx, a.B0, a.b0,
        a.g0, a.be0, a.rm0, a.rv0, a.h0);
    layer_kernel<256><<<GRID, 256, 0, stream>>>(a.h0, a.ptr, a.idx, a.B1, a.b1,
        a.g1, a.be1, a.rm1, a.rv1, a.h1);
    proj2_kernel<<<(ROWS + 63) / 64, 256, 0, stream>>>(a.h1, a.Bp2, a.y2w, a.y2r);
    combine2_kernel<<<ROWS / 16, 256, 0, stream>>>(a.ptr, a.idx, a.y2w, a.y2r, a.b2, a.out);
}

// Round 9
// 60.475 us; speedup vs baseline: 1.1208x; 1.1208x over previous
//
#include <hip/hip_runtime.h>
#include <cmath>

// HistorySAGE: 3 GraphSAGE layers, only the 20000 live rows computed per layer
// (idx < 20000, output rows < 20000). Multi-launch (coop grid.sync measured
// 3.2x slower, round 4). Round 9: proj2 fused INTO layer 1 — the h1 tile is
// round-tripped through LDS and projected to 96 cols in-kernel, eliminating
// the h1 global buffer (20 MB traffic) and one kernel launch.
constexpr int ROWS = 20000;
constexpr int BM   = 32;             // rows per block tile for layers 0/1
constexpr int GRID = ROWS / BM;      // 625 blocks
constexpr float BN_EPS = 1e-5f;

using f32x4  = __attribute__((ext_vector_type(4))) float;
using short8 = __attribute__((ext_vector_type(8))) short;

__device__ __forceinline__ float bf2f(unsigned short u) {
    unsigned int x = ((unsigned int)u) << 16;
    return __builtin_bit_cast(float, x);
}
__device__ __forceinline__ unsigned short f2bf(float f) {
    unsigned int x = __builtin_bit_cast(unsigned int, f);
    unsigned int r = x + 0x7fffu + ((x >> 16) & 1u);   // RNE
    return (unsigned short)(r >> 16);
}

// Fragment-major weight layout: Bf[((n16*K32 + k32)*64 + lane)*8 + q] =
// bf16 of Wcat[k32*32 + (lane>>4)*8 + q][n16*16 + (lane&15)], Wcat = [W; R].
// A wave reading lane*8 shorts at a (n16,k32) block base gets its exact
// 16x16x32 MFMA B-fragment fully coalesced (1KB/wave).
__device__ __forceinline__ void convw_frag(const float* __restrict__ W, const float* __restrict__ R,
                                           unsigned short* __restrict__ B, int K, int Ntrue, int N16,
                                           int gtid, int gstride)
{
    const int K32 = 2 * K / 32;
    const int total = N16 * K32 * 64;
    for (int j = gtid; j < total; j += gstride) {
        const int lane = j & 63;
        const int rest = j >> 6;
        const int k32 = rest % K32, n16 = rest / K32;
        const int n  = n16 * 16 + (lane & 15);
        const int kb = k32 * 32 + (lane >> 4) * 8;
        short8 o;
        #pragma unroll
        for (int q = 0; q < 8; ++q) {
            const int kk = kb + q;
            float v = 0.f;
            if (n < Ntrue) v = (kk < K) ? W[(size_t)kk * Ntrue + n] : R[(size_t)(kk - K) * Ntrue + n];
            o[q] = (short)f2bf(v);
        }
        *(short8*)(B + (size_t)j * 8) = o;
    }
}

// Layer-2 projection weights, single-K frag layout (K=256, 6 col-tiles):
// n<47 -> W2[k][n]; 48<=n<95 -> R2[k][n-48]; else 0.
__device__ __forceinline__ void convw_proj2(const float* __restrict__ W, const float* __restrict__ R,
                                            unsigned short* __restrict__ B, int gtid, int gstride)
{
    constexpr int KS = 8;                 // 256/32
    const int total = 6 * KS * 64;
    for (int j = gtid; j < total; j += gstride) {
        const int lane = j & 63, rest = j >> 6;
        const int ks = rest % KS, t = rest / KS;
        const int n  = t * 16 + (lane & 15);
        const int kb = ks * 32 + (lane >> 4) * 8;
        short8 o;
        #pragma unroll
        for (int q = 0; q < 8; ++q) {
            const int kk = kb + q;
            float v = 0.f;
            if (n < 47)                 v = W[(size_t)kk * 47 + n];
            else if (n >= 48 && n < 95) v = R[(size_t)kk * 47 + (n - 48)];
            o[q] = (short)f2bf(v);
        }
        *(short8*)(B + (size_t)j * 8) = o;
    }
}

struct Args {
    const float* x; const int* ptr; const int* idx;
    const float *W0, *b0, *R0, *W1, *b1, *R1, *W2, *b2, *R2;
    const float *g0, *be0, *rm0, *rv0, *g1, *be1, *rm1, *rv1;
    unsigned short *B0, *B1, *Bp2, *xb, *h0, *y2w, *y2r;
    float* out;
};

// prep: x rows [0,ROWS) -> bf16 + all weight buffers.
__global__ __launch_bounds__(256) void prep(Args a)
{
    const int gtid = blockIdx.x * 256 + threadIdx.x, gstride = gridDim.x * 256;
    for (int i = gtid; i < ROWS * 16; i += gstride) {
        const int row = i >> 4, c = (i & 15) * 8;
        const float4 v0 = *(const float4*)(a.x + (size_t)row * 128 + c);
        const float4 v1 = *(const float4*)(a.x + (size_t)row * 128 + c + 4);
        short8 o;
        o[0]=(short)f2bf(v0.x); o[1]=(short)f2bf(v0.y); o[2]=(short)f2bf(v0.z); o[3]=(short)f2bf(v0.w);
        o[4]=(short)f2bf(v1.x); o[5]=(short)f2bf(v1.y); o[6]=(short)f2bf(v1.z); o[7]=(short)f2bf(v1.w);
        *(short8*)(a.xb + (size_t)row * 128 + c) = o;
    }
    convw_frag(a.W0, a.R0, a.B0, 128, 256, 16, gtid, gstride);
    convw_frag(a.W1, a.R1, a.B1, 256, 256, 16, gtid, gstride);
    convw_proj2(a.W2, a.R2, a.Bp2, gtid, gstride);
}

// ---- layer phase helpers (proven round-7 structure) ----

template<int K>
__device__ __forceinline__ void gather_agg(const unsigned short* __restrict__ src,
    const int* __restrict__ idx, const int* sIdx, const int* sOff, const int* sCnt,
    const float* sInv, unsigned short* sA, int tid)
{
    constexpr int KA = K + 8, CA = K / 8;
    for (int u = tid; u < BM * CA; u += 256) {
        const int r = u / CA, c = (u - (u / CA) * CA) * 8;
        const int cnt = sCnt[r];
        float acc[8];
        #pragma unroll
        for (int q = 0; q < 8; ++q) acc[q] = 0.f;
        if (__builtin_expect(cnt == 10, 1)) {
            int nb[10];
            #pragma unroll
            for (int j = 0; j < 10; ++j) nb[j] = sIdx[r * 10 + j];
            short8 v[10];
            #pragma unroll
            for (int j = 0; j < 10; ++j) v[j] = *(const short8*)(src + (size_t)nb[j] * K + c);
            #pragma unroll
            for (int j = 0; j < 10; ++j)
                #pragma unroll
                for (int q = 0; q < 8; ++q) acc[q] += bf2f((unsigned short)v[j][q]);
        } else {
            for (int p = 0; p < cnt; ++p) {
                const int nb = idx[sOff[r] + p];
                const short8 v = *(const short8*)(src + (size_t)nb * K + c);
                #pragma unroll
                for (int q = 0; q < 8; ++q) acc[q] += bf2f((unsigned short)v[q]);
            }
        }
        const float inv = sInv[r];
        short8 o;
        #pragma unroll
        for (int q = 0; q < 8; ++q) o[q] = (short)f2bf(acc[q] * inv);
        *(short8*)(&sA[r * KA + c]) = o;
    }
}

template<int K>
__device__ __forceinline__ void self_gemm256(const unsigned short* __restrict__ src,
    const unsigned short* __restrict__ Bf, int rowBase, int lane, int wid, f32x4 (&acc)[2][4])
{
    constexpr int KS_A = K / 32, KS_T = 2 * K / 32;
    const int mrow = lane & 15, kg = (lane >> 4) * 8;
    const int nt0 = wid * 4;
    #pragma unroll
    for (int ks2 = 0; ks2 < KS_A; ++ks2) {
        const int kc = ks2 * 32 + kg;
        const short8 a0 = *(const short8*)(src + (size_t)(rowBase + mrow) * K + kc);
        const short8 a1 = *(const short8*)(src + (size_t)(rowBase + 16 + mrow) * K + kc);
        #pragma unroll
        for (int t = 0; t < 4; ++t) {
            const short8 b = *(const short8*)(Bf + ((size_t)(nt0 + t) * KS_T + KS_A + ks2) * 512 + lane * 8);
            acc[0][t] = __builtin_amdgcn_mfma_f32_16x16x32_bf16(a0, b, acc[0][t], 0, 0, 0);
            acc[1][t] = __builtin_amdgcn_mfma_f32_16x16x32_bf16(a1, b, acc[1][t], 0, 0, 0);
        }
    }
}

template<int K>
__device__ __forceinline__ void agg_gemm256(const unsigned short* sA,
    const unsigned short* __restrict__ Bf, int lane, int wid, f32x4 (&acc)[2][4])
{
    constexpr int KA = K + 8, KS_A = K / 32, KS_T = 2 * K / 32;
    const int mrow = lane & 15, kg = (lane >> 4) * 8;
    const int nt0 = wid * 4;
    #pragma unroll
    for (int ks = 0; ks < KS_A; ++ks) {
        const short8 a0 = *(const short8*)(&sA[mrow * KA + ks * 32 + kg]);
        const short8 a1 = *(const short8*)(&sA[(16 + mrow) * KA + ks * 32 + kg]);
        #pragma unroll
        for (int t = 0; t < 4; ++t) {
            const short8 b = *(const short8*)(Bf + ((size_t)(nt0 + t) * KS_T + ks) * 512 + lane * 8);
            acc[0][t] = __builtin_amdgcn_mfma_f32_16x16x32_bf16(a0, b, acc[0][t], 0, 0, 0);
            acc[1][t] = __builtin_amdgcn_mfma_f32_16x16x32_bf16(a1, b, acc[1][t], 0, 0, 0);
        }
    }
}

// 32 rows x 256 cols, BN+ReLU, block-parity phase stagger.
// PROJ=false: store h tile -> dstB (bf16 global).
// PROJ=true : round-trip h tile through LDS, project to 96 cols with Bp2
//             (y2w = h@W2, y2r = h@R2), store only those (h never hits global).
template<int K, bool PROJ>
__global__ __launch_bounds__(256, 3)
void layer_kernel(const unsigned short* __restrict__ src,
                  const int* __restrict__ ptr, const int* __restrict__ idx,
                  const unsigned short* __restrict__ Bf, const float* __restrict__ bias,
                  const float* __restrict__ gam, const float* __restrict__ bet,
                  const float* __restrict__ rmean, const float* __restrict__ rvar,
                  unsigned short* __restrict__ dstB,
                  const unsigned short* __restrict__ Bp2,
                  unsigned short* __restrict__ y2w,
                  unsigned short* __restrict__ y2r)
{
    constexpr int KA = K + 8;
    __shared__ unsigned short sA[BM * KA];   // agg tile, then (PROJ) h tile
    __shared__ int   sIdx[BM * 10];
    __shared__ int   sOff[BM];
    __shared__ int   sCnt[BM];
    __shared__ float sInv[BM];

    const int tid = threadIdx.x;
    const int rowBase = blockIdx.x * BM;
    const bool evenBlk = (blockIdx.x & 1) == 0;   // block-uniform

    if (tid < BM) {
        const int p0 = ptr[rowBase + tid], p1 = ptr[rowBase + tid + 1];
        sOff[tid] = p0; sCnt[tid] = p1 - p0; sInv[tid] = 1.0f / (float)(p1 - p0);
    }
    __syncthreads();
    for (int u = tid; u < BM * 10; u += 256) {
        const int r = u / 10, j = u - r * 10;
        sIdx[u] = (j < sCnt[r]) ? idx[sOff[r] + j] : 0;
    }
    __syncthreads();

    const int lane = tid & 63, wid = tid >> 6;
    const int mrow = lane & 15;

    f32x4 acc[2][4];
    #pragma unroll
    for (int i = 0; i < 2; ++i)
        #pragma unroll
        for (int t = 0; t < 4; ++t) acc[i][t] = (f32x4){0.f, 0.f, 0.f, 0.f};

    if (evenBlk) {
        self_gemm256<K>(src, Bf, rowBase, lane, wid, acc);
        gather_agg<K>(src, idx, sIdx, sOff, sCnt, sInv, sA, tid);
        __syncthreads();
        agg_gemm256<K>(sA, Bf, lane, wid, acc);
    } else {
        gather_agg<K>(src, idx, sIdx, sOff, sCnt, sInv, sA, tid);
        __syncthreads();
        self_gemm256<K>(src, Bf, rowBase, lane, wid, acc);
        agg_gemm256<K>(sA, Bf, lane, wid, acc);
    }

    const int nt0 = wid * 4;
    if constexpr (!PROJ) {
        #pragma unroll
        for (int t = 0; t < 4; ++t) {
            const int col = (nt0 + t) * 16 + mrow;
            const float sc = gam[col] * rsqrtf(rvar[col] + BN_EPS);
            const float sh = bet[col] - rmean[col] * sc;
            const float bb = bias[col];
            #pragma unroll
            for (int i = 0; i < 2; ++i)
                #pragma unroll
                for (int reg = 0; reg < 4; ++reg) {
                    const int row = rowBase + i * 16 + (lane >> 4) * 4 + reg;
                    float h = acc[i][t][reg] + bb;
                    h = fmaxf(h * sc + sh, 0.f);
                    dstB[(size_t)row * 256 + col] = f2bf(h);
                }
        }
    } else {
        // ---- epilogue -> LDS h tile (reuse sA: [32][KA] with KA=264) ----
        __syncthreads();                      // all agg_gemm reads of sA done
        #pragma unroll
        for (int t = 0; t < 4; ++t) {
            const int col = (nt0 + t) * 16 + mrow;
            const float sc = gam[col] * rsqrtf(rvar[col] + BN_EPS);
            const float sh = bet[col] - rmean[col] * sc;
            const float bb = bias[col];
            #pragma unroll
            for (int i = 0; i < 2; ++i)
                #pragma unroll
                for (int reg = 0; reg < 4; ++reg) {
                    const int rl = i * 16 + (lane >> 4) * 4 + reg;
                    float h = acc[i][t][reg] + bb;
                    h = fmaxf(h * sc + sh, 0.f);
                    sA[rl * KA + col] = f2bf(h);
                }
        }
        __syncthreads();
        // ---- projection: 32 rows x 96 cols, K=256; waves 0..2 x 2 col-tiles ----
        if (wid < 3) {
            constexpr int KS = K / 32;        // 8
            const int kg = (lane >> 4) * 8;
            f32x4 pacc[2][2];
            #pragma unroll
            for (int i = 0; i < 2; ++i)
                #pragma unroll
                for (int tt = 0; tt < 2; ++tt) pacc[i][tt] = (f32x4){0.f, 0.f, 0.f, 0.f};
            #pragma unroll
            for (int ks = 0; ks < KS; ++ks) {
                const short8 a0 = *(const short8*)(&sA[mrow * KA + ks * 32 + kg]);
                const short8 a1 = *(const short8*)(&sA[(16 + mrow) * KA + ks * 32 + kg]);
                #pragma unroll
                for (int tt = 0; tt < 2; ++tt) {
                    const int t = wid * 2 + tt;
                    const short8 b = *(const short8*)(Bp2 + ((size_t)t * KS + ks) * 512 + lane * 8);
                    pacc[0][tt] = __builtin_amdgcn_mfma_f32_16x16x32_bf16(a0, b, pacc[0][tt], 0, 0, 0);
                    pacc[1][tt] = __builtin_amdgcn_mfma_f32_16x16x32_bf16(a1, b, pacc[1][tt], 0, 0, 0);
                }
            }
            #pragma unroll
            for (int tt = 0; tt < 2; ++tt) {
                const int col = (wid * 2 + tt) * 16 + mrow;
                #pragma unroll
                for (int i = 0; i < 2; ++i)
                    #pragma unroll
                    for (int reg = 0; reg < 4; ++reg) {
                        const int row = rowBase + i * 16 + (lane >> 4) * 4 + reg;
                        const unsigned short v = f2bf(pacc[i][tt][reg]);
                        if (col < 48) y2w[(size_t)row * 48 + col] = v;
                        else          y2r[(size_t)row * 48 + (col - 48)] = v;
                    }
            }
        }
    }
}

// combine2: out[r] = log_softmax(mean_nb(y2w) + y2r[r] + b2). 16 rows/block,
// 16 lanes per row (cols c, c+16, c+32). Gathers 96B rows (L2-resident buffer).
__global__ __launch_bounds__(256)
void combine2_kernel(const int* __restrict__ ptr, const int* __restrict__ idx,
                     const unsigned short* __restrict__ y2w,
                     const unsigned short* __restrict__ y2r,
                     const float* __restrict__ b2,
                     float* __restrict__ out)
{
    const int tid = threadIdx.x, lane = tid & 63, wid = tid >> 6;
    const int c = lane & 15, sub = lane >> 4;
    const int row = blockIdx.x * 16 + wid * 4 + sub;
    const int p0 = ptr[row], p1 = ptr[row + 1];
    const float inv = 1.0f / (float)(p1 - p0);
    float s0 = 0.f, s1 = 0.f, s2 = 0.f;
    for (int p = p0; p < p1; ++p) {
        const int nb = idx[p];
        const unsigned short* yr = y2w + (size_t)nb * 48;
        s0 += bf2f(yr[c]); s1 += bf2f(yr[16 + c]); s2 += bf2f(yr[32 + c]);
    }
    const unsigned short* sr = y2r + (size_t)row * 48;
    const bool ok2 = (32 + c) < 47;
    float v0 = s0 * inv + bf2f(sr[c])      + b2[c];
    float v1 = s1 * inv + bf2f(sr[16 + c]) + b2[16 + c];
    float v2 = ok2 ? (s2 * inv + bf2f(sr[32 + c]) + b2[32 + c]) : -3.0e38f;
    float mx = fmaxf(fmaxf(v0, v1), v2);
    #pragma unroll
    for (int o = 1; o < 16; o <<= 1) mx = fmaxf(mx, __shfl_xor(mx, o, 16));
    float s = expf(v0 - mx) + expf(v1 - mx) + (ok2 ? expf(v2 - mx) : 0.f);
    #pragma unroll
    for (int o = 1; o < 16; o <<= 1) s += __shfl_xor(s, o, 16);
    const float ls = mx + logf(s);
    out[(size_t)row * 47 + c]      = v0 - ls;
    out[(size_t)row * 47 + 16 + c] = v1 - ls;
    if (ok2) out[(size_t)row * 47 + 32 + c] = v2 - ls;
}

extern "C" void kernel_launch(void* const* d_in, const int* in_sizes, int n_in,
                              void* d_out, int out_size, void* d_ws, size_t ws_size,
                              hipStream_t stream)
{
    char* ws = (char*)d_ws;
    Args a;
    a.x   = (const float*)d_in[0];
    a.ptr = (const int*)d_in[1];
    a.idx = (const int*)d_in[2];
    a.W0  = (const float*)d_in[3];  a.b0 = (const float*)d_in[4];  a.R0 = (const float*)d_in[5];
    a.W1  = (const float*)d_in[6];  a.b1 = (const float*)d_in[7];  a.R1 = (const float*)d_in[8];
    a.W2  = (const float*)d_in[9];  a.b2 = (const float*)d_in[10]; a.R2 = (const float*)d_in[11];
    a.g0  = (const float*)d_in[12]; a.be0 = (const float*)d_in[13];
    a.rm0 = (const float*)d_in[14]; a.rv0 = (const float*)d_in[15];
    a.g1  = (const float*)d_in[16]; a.be1 = (const float*)d_in[17];
    a.rm1 = (const float*)d_in[18]; a.rv1 = (const float*)d_in[19];
    a.B0  = (unsigned short*)(ws);                        // 128 KB
    a.B1  = (unsigned short*)(ws + 131072);               // 256 KB
    a.Bp2 = (unsigned short*)(ws + 393216);               //  48 KB
    a.xb  = (unsigned short*)(ws + 442368);               // 20000*128 bf16 = 5.12 MB
    a.h0  = (unsigned short*)(ws + 5562368);              // 20000*256 bf16 = 10.24 MB
    a.y2w = (unsigned short*)(ws + 15802368);             // 20000*48 bf16 = 1.92 MB
    a.y2r = (unsigned short*)(ws + 17722368);             // 20000*48 bf16
    a.out = (float*)d_out;

    prep<<<1280, 256, 0, stream>>>(a);
    layer_kernel<128, false><<<GRID, 256, 0, stream>>>(a.xb, a.ptr, a.idx, a.B0, a.b0,
        a.g0, a.be0, a.rm0, a.rv0, a.h0, nullptr, nullptr, nullptr);
    layer_kernel<256, true ><<<GRID, 256, 0, stream>>>(a.h0, a.ptr, a.idx, a.B1, a.b1,
        a.g1, a.be1, a.rm1, a.rv1, nullptr, a.Bp2, a.y2w, a.y2r);
    combine2_kernel<<<ROWS / 16, 256, 0, stream>>>(a.ptr, a.idx, a.y2w, a.y2r, a.b2, a.out);
}

// Round 11
// 59.086 us; speedup vs baseline: 1.1471x; 1.0235x over previous
//
#include <hip/hip_runtime.h>
#include <cmath>

// HistorySAGE: 3 GraphSAGE layers, only the 20000 live rows computed per layer
// (idx < 20000, output rows < 20000). 4 plain launches (coop grid.sync measured
// 3.2x slower, round 4). Round 11: fp8(e4m3) storage for the GATHER operand
// only (mean-of-10 averages fp8 noise down; self path stays bf16) — gather
// traffic 153 -> 77 MB. HW cvt: v_cvt_f32_fp8 / v_cvt_pk_fp8_f32.
// (round-10 fix: cvt_f32_fp8 lane-select must be a literal constant.)
constexpr int ROWS = 20000;
constexpr int BM   = 32;             // rows per block tile (20000 = 625*32 exact)
constexpr int GRID = ROWS / BM;      // 625 blocks
constexpr float BN_EPS = 1e-5f;

using f32x4  = __attribute__((ext_vector_type(4))) float;
using short8 = __attribute__((ext_vector_type(8))) short;

__device__ __forceinline__ float bf2f(unsigned short u) {
    unsigned int x = ((unsigned int)u) << 16;
    return __builtin_bit_cast(float, x);
}
__device__ __forceinline__ unsigned short f2bf(float f) {
    unsigned int x = __builtin_bit_cast(unsigned int, f);
    unsigned int r = x + 0x7fffu + ((x >> 16) & 1u);   // RNE
    return (unsigned short)(r >> 16);
}
__device__ __forceinline__ unsigned char f2fp8(float f) {
    return (unsigned char)(__builtin_amdgcn_cvt_pk_fp8_f32(f, f, 0, false) & 0xFF);
}
// acc[0..7] += fp8x8 from uint2 (lane selects are literal constants)
__device__ __forceinline__ void acc_fp8x8(float* acc, uint2 v) {
    acc[0] += __builtin_amdgcn_cvt_f32_fp8((int)v.x, 0);
    acc[1] += __builtin_amdgcn_cvt_f32_fp8((int)v.x, 1);
    acc[2] += __builtin_amdgcn_cvt_f32_fp8((int)v.x, 2);
    acc[3] += __builtin_amdgcn_cvt_f32_fp8((int)v.x, 3);
    acc[4] += __builtin_amdgcn_cvt_f32_fp8((int)v.y, 0);
    acc[5] += __builtin_amdgcn_cvt_f32_fp8((int)v.y, 1);
    acc[6] += __builtin_amdgcn_cvt_f32_fp8((int)v.y, 2);
    acc[7] += __builtin_amdgcn_cvt_f32_fp8((int)v.y, 3);
}

// Fragment-major weight layout: Bf[((n16*K32 + k32)*64 + lane)*8 + q] =
// bf16 of Wcat[k32*32 + (lane>>4)*8 + q][n16*16 + (lane&15)], Wcat = [W; R].
// A wave reading lane*8 shorts at a (n16,k32) block base gets its exact
// 16x16x32 MFMA B-fragment fully coalesced (1KB/wave).
__device__ __forceinline__ void convw_frag(const float* __restrict__ W, const float* __restrict__ R,
                                           unsigned short* __restrict__ B, int K, int Ntrue, int N16,
                                           int gtid, int gstride)
{
    const int K32 = 2 * K / 32;
    const int total = N16 * K32 * 64;
    for (int j = gtid; j < total; j += gstride) {
        const int lane = j & 63;
        const int rest = j >> 6;
        const int k32 = rest % K32, n16 = rest / K32;
        const int n  = n16 * 16 + (lane & 15);
        const int kb = k32 * 32 + (lane >> 4) * 8;
        short8 o;
        #pragma unroll
        for (int q = 0; q < 8; ++q) {
            const int kk = kb + q;
            float v = 0.f;
            if (n < Ntrue) v = (kk < K) ? W[(size_t)kk * Ntrue + n] : R[(size_t)(kk - K) * Ntrue + n];
            o[q] = (short)f2bf(v);
        }
        *(short8*)(B + (size_t)j * 8) = o;
    }
}

// Layer-2 projection weights, single-K frag layout (K=256, 6 col-tiles):
// n<47 -> W2[k][n]; 48<=n<95 -> R2[k][n-48]; else 0.
__device__ __forceinline__ void convw_proj2(const float* __restrict__ W, const float* __restrict__ R,
                                            unsigned short* __restrict__ B, int gtid, int gstride)
{
    constexpr int KS = 8;                 // 256/32
    const int total = 6 * KS * 64;
    for (int j = gtid; j < total; j += gstride) {
        const int lane = j & 63, rest = j >> 6;
        const int ks = rest % KS, t = rest / KS;
        const int n  = t * 16 + (lane & 15);
        const int kb = ks * 32 + (lane >> 4) * 8;
        short8 o;
        #pragma unroll
        for (int q = 0; q < 8; ++q) {
            const int kk = kb + q;
            float v = 0.f;
            if (n < 47)                 v = W[(size_t)kk * 47 + n];
            else if (n >= 48 && n < 95) v = R[(size_t)kk * 47 + (n - 48)];
            o[q] = (short)f2bf(v);
        }
        *(short8*)(B + (size_t)j * 8) = o;
    }
}

struct Args {
    const float* x; const int* ptr; const int* idx;
    const float *W0, *b0, *R0, *W1, *b1, *R1, *W2, *b2, *R2;
    const float *g0, *be0, *rm0, *rv0, *g1, *be1, *rm1, *rv1;
    unsigned short *B0, *B1, *Bp2, *xb, *h0, *y2w, *y2r;
    unsigned char *xb8, *h08;
    float* out;
};

// prep: x rows [0,ROWS) -> bf16 (self path) + fp8 (gather path) + weights.
__global__ __launch_bounds__(256) void prep(Args a)
{
    const int gtid = blockIdx.x * 256 + threadIdx.x, gstride = gridDim.x * 256;
    for (int i = gtid; i < ROWS * 16; i += gstride) {
        const int row = i >> 4, c = (i & 15) * 8;
        const float4 v0 = *(const float4*)(a.x + (size_t)row * 128 + c);
        const float4 v1 = *(const float4*)(a.x + (size_t)row * 128 + c + 4);
        short8 o;
        o[0]=(short)f2bf(v0.x); o[1]=(short)f2bf(v0.y); o[2]=(short)f2bf(v0.z); o[3]=(short)f2bf(v0.w);
        o[4]=(short)f2bf(v1.x); o[5]=(short)f2bf(v1.y); o[6]=(short)f2bf(v1.z); o[7]=(short)f2bf(v1.w);
        *(short8*)(a.xb + (size_t)row * 128 + c) = o;
        uint2 p;
        p.x = (unsigned int)__builtin_amdgcn_cvt_pk_fp8_f32(v0.x, v0.y, 0, false);
        p.x = (unsigned int)__builtin_amdgcn_cvt_pk_fp8_f32(v0.z, v0.w, (int)p.x, true);
        p.y = (unsigned int)__builtin_amdgcn_cvt_pk_fp8_f32(v1.x, v1.y, 0, false);
        p.y = (unsigned int)__builtin_amdgcn_cvt_pk_fp8_f32(v1.z, v1.w, (int)p.y, true);
        *(uint2*)(a.xb8 + (size_t)row * 128 + c) = p;
    }
    convw_frag(a.W0, a.R0, a.B0, 128, 256, 16, gtid, gstride);
    convw_frag(a.W1, a.R1, a.B1, 256, 256, 16, gtid, gstride);
    convw_proj2(a.W2, a.R2, a.Bp2, gtid, gstride);
}

// ---- phase helpers ----

// 10-neighbor mean rows (fp8 source) -> LDS (bf16).
template<int K>
__device__ __forceinline__ void gather_agg8(const unsigned char* __restrict__ src8,
    const int* __restrict__ idx, const int* sIdx, const int* sOff, const int* sCnt,
    const float* sInv, unsigned short* sA, int tid)
{
    constexpr int KA = K + 8, CA = K / 8;
    for (int u = tid; u < BM * CA; u += 256) {
        const int r = u / CA, c = (u - (u / CA) * CA) * 8;
        const int cnt = sCnt[r];
        float acc[8];
        #pragma unroll
        for (int q = 0; q < 8; ++q) acc[q] = 0.f;
        if (__builtin_expect(cnt == 10, 1)) {
            int nb[10];
            #pragma unroll
            for (int j = 0; j < 10; ++j) nb[j] = sIdx[r * 10 + j];
            uint2 v[10];
            #pragma unroll
            for (int j = 0; j < 10; ++j) v[j] = *(const uint2*)(src8 + (size_t)nb[j] * K + c);
            #pragma unroll
            for (int j = 0; j < 10; ++j) acc_fp8x8(acc, v[j]);
        } else {
            for (int p = 0; p < cnt; ++p) {
                const int nb = idx[sOff[r] + p];
                const uint2 v = *(const uint2*)(src8 + (size_t)nb * K + c);
                acc_fp8x8(acc, v);
            }
        }
        const float inv = sInv[r];
        short8 o;
        #pragma unroll
        for (int q = 0; q < 8; ++q) o[q] = (short)f2bf(acc[q] * inv);
        *(short8*)(&sA[r * KA + c]) = o;
    }
}

template<int K>
__device__ __forceinline__ void self_gemm256(const unsigned short* __restrict__ src,
    const unsigned short* __restrict__ Bf, int rowBase, int lane, int wid, f32x4 (&acc)[2][4])
{
    constexpr int KS_A = K / 32, KS_T = 2 * K / 32;
    const int mrow = lane & 15, kg = (lane >> 4) * 8;
    const int nt0 = wid * 4;
    #pragma unroll
    for (int ks2 = 0; ks2 < KS_A; ++ks2) {
        const int kc = ks2 * 32 + kg;
        const short8 a0 = *(const short8*)(src + (size_t)(rowBase + mrow) * K + kc);
        const short8 a1 = *(const short8*)(src + (size_t)(rowBase + 16 + mrow) * K + kc);
        #pragma unroll
        for (int t = 0; t < 4; ++t) {
            const short8 b = *(const short8*)(Bf + ((size_t)(nt0 + t) * KS_T + KS_A + ks2) * 512 + lane * 8);
            acc[0][t] = __builtin_amdgcn_mfma_f32_16x16x32_bf16(a0, b, acc[0][t], 0, 0, 0);
            acc[1][t] = __builtin_amdgcn_mfma_f32_16x16x32_bf16(a1, b, acc[1][t], 0, 0, 0);
        }
    }
}

template<int K>
__device__ __forceinline__ void agg_gemm256(const unsigned short* sA,
    const unsigned short* __restrict__ Bf, int lane, int wid, f32x4 (&acc)[2][4])
{
    constexpr int KA = K + 8, KS_A = K / 32, KS_T = 2 * K / 32;
    const int mrow = lane & 15, kg = (lane >> 4) * 8;
    const int nt0 = wid * 4;
    #pragma unroll
    for (int ks = 0; ks < KS_A; ++ks) {
        const short8 a0 = *(const short8*)(&sA[mrow * KA + ks * 32 + kg]);
        const short8 a1 = *(const short8*)(&sA[(16 + mrow) * KA + ks * 32 + kg]);
        #pragma unroll
        for (int t = 0; t < 4; ++t) {
            const short8 b = *(const short8*)(Bf + ((size_t)(nt0 + t) * KS_T + ks) * 512 + lane * 8);
            acc[0][t] = __builtin_amdgcn_mfma_f32_16x16x32_bf16(a0, b, acc[0][t], 0, 0, 0);
            acc[1][t] = __builtin_amdgcn_mfma_f32_16x16x32_bf16(a1, b, acc[1][t], 0, 0, 0);
        }
    }
}

// 32 rows x 256 cols, BN+ReLU, block-parity phase stagger.
// PROJ=false: store h tile -> dstB (bf16) + dst8 (fp8, next layer's gather).
// PROJ=true : round-trip h tile through LDS, project to 96 cols with Bp2
//             (y2w = h@W2, y2r = h@R2), store only those.
template<int K, bool PROJ>
__global__ __launch_bounds__(256, 3)
void layer_kernel(const unsigned short* __restrict__ src,
                  const unsigned char* __restrict__ src8,
                  const int* __restrict__ ptr, const int* __restrict__ idx,
                  const unsigned short* __restrict__ Bf, const float* __restrict__ bias,
                  const float* __restrict__ gam, const float* __restrict__ bet,
                  const float* __restrict__ rmean, const float* __restrict__ rvar,
                  unsigned short* __restrict__ dstB,
                  unsigned char* __restrict__ dst8,
                  const unsigned short* __restrict__ Bp2,
                  unsigned short* __restrict__ y2w,
                  unsigned short* __restrict__ y2r)
{
    constexpr int KA = K + 8;
    __shared__ unsigned short sA[BM * KA];   // agg tile, then (PROJ) h tile
    __shared__ int   sIdx[BM * 10];
    __shared__ int   sOff[BM];
    __shared__ int   sCnt[BM];
    __shared__ float sInv[BM];

    const int tid = threadIdx.x;
    const int rowBase = blockIdx.x * BM;
    const bool evenBlk = (blockIdx.x & 1) == 0;   // block-uniform

    if (tid < BM) {
        const int p0 = ptr[rowBase + tid], p1 = ptr[rowBase + tid + 1];
        sOff[tid] = p0; sCnt[tid] = p1 - p0; sInv[tid] = 1.0f / (float)(p1 - p0);
    }
    __syncthreads();
    for (int u = tid; u < BM * 10; u += 256) {
        const int r = u / 10, j = u - r * 10;
        sIdx[u] = (j < sCnt[r]) ? idx[sOff[r] + j] : 0;
    }
    __syncthreads();

    const int lane = tid & 63, wid = tid >> 6;
    const int mrow = lane & 15;

    f32x4 acc[2][4];
    #pragma unroll
    for (int i = 0; i < 2; ++i)
        #pragma unroll
        for (int t = 0; t < 4; ++t) acc[i][t] = (f32x4){0.f, 0.f, 0.f, 0.f};

    if (evenBlk) {
        self_gemm256<K>(src, Bf, rowBase, lane, wid, acc);
        gather_agg8<K>(src8, idx, sIdx, sOff, sCnt, sInv, sA, tid);
        __syncthreads();
        agg_gemm256<K>(sA, Bf, lane, wid, acc);
    } else {
        gather_agg8<K>(src8, idx, sIdx, sOff, sCnt, sInv, sA, tid);
        __syncthreads();
        self_gemm256<K>(src, Bf, rowBase, lane, wid, acc);
        agg_gemm256<K>(sA, Bf, lane, wid, acc);
    }

    const int nt0 = wid * 4;
    if constexpr (!PROJ) {
        #pragma unroll
        for (int t = 0; t < 4; ++t) {
            const int col = (nt0 + t) * 16 + mrow;
            const float sc = gam[col] * rsqrtf(rvar[col] + BN_EPS);
            const float sh = bet[col] - rmean[col] * sc;
            const float bb = bias[col];
            #pragma unroll
            for (int i = 0; i < 2; ++i)
                #pragma unroll
                for (int reg = 0; reg < 4; ++reg) {
                    const int row = rowBase + i * 16 + (lane >> 4) * 4 + reg;
                    float h = acc[i][t][reg] + bb;
                    h = fmaxf(h * sc + sh, 0.f);
                    dstB[(size_t)row * 256 + col] = f2bf(h);
                    dst8[(size_t)row * 256 + col] = f2fp8(h);
                }
        }
    } else {
        // ---- epilogue -> LDS h tile (reuse sA: [32][KA] with KA=264) ----
        __syncthreads();                      // all agg_gemm reads of sA done
        #pragma unroll
        for (int t = 0; t < 4; ++t) {
            const int col = (nt0 + t) * 16 + mrow;
            const float sc = gam[col] * rsqrtf(rvar[col] + BN_EPS);
            const float sh = bet[col] - rmean[col] * sc;
            const float bb = bias[col];
            #pragma unroll
            for (int i = 0; i < 2; ++i)
                #pragma unroll
                for (int reg = 0; reg < 4; ++reg) {
                    const int rl = i * 16 + (lane >> 4) * 4 + reg;
                    float h = acc[i][t][reg] + bb;
                    h = fmaxf(h * sc + sh, 0.f);
                    sA[rl * KA + col] = f2bf(h);
                }
        }
        __syncthreads();
        // ---- projection: 32 rows x 96 cols, K=256; waves 0..2 x 2 col-tiles ----
        if (wid < 3) {
            constexpr int KS = K / 32;        // 8
            const int kg = (lane >> 4) * 8;
            f32x4 pacc[2][2];
            #pragma unroll
            for (int i = 0; i < 2; ++i)
                #pragma unroll
                for (int tt = 0; tt < 2; ++tt) pacc[i][tt] = (f32x4){0.f, 0.f, 0.f, 0.f};
            #pragma unroll
            for (int ks = 0; ks < KS; ++ks) {
                const short8 a0 = *(const short8*)(&sA[mrow * KA + ks * 32 + kg]);
                const short8 a1 = *(const short8*)(&sA[(16 + mrow) * KA + ks * 32 + kg]);
                #pragma unroll
                for (int tt = 0; tt < 2; ++tt) {
                    const int t = wid * 2 + tt;
                    const short8 b = *(const short8*)(Bp2 + ((size_t)t * KS + ks) * 512 + lane * 8);
                    pacc[0][tt] = __builtin_amdgcn_mfma_f32_16x16x32_bf16(a0, b, pacc[0][tt], 0, 0, 0);
                    pacc[1][tt] = __builtin_amdgcn_mfma_f32_16x16x32_bf16(a1, b, pacc[1][tt], 0, 0, 0);
                }
            }
            #pragma unroll
            for (int tt = 0; tt < 2; ++tt) {
                const int col = (wid * 2 + tt) * 16 + mrow;
                #pragma unroll
                for (int i = 0; i < 2; ++i)
                    #pragma unroll
                    for (int reg = 0; reg < 4; ++reg) {
                        const int row = rowBase + i * 16 + (lane >> 4) * 4 + reg;
                        const unsigned short v = f2bf(pacc[i][tt][reg]);
                        if (col < 48) y2w[(size_t)row * 48 + col] = v;
                        else          y2r[(size_t)row * 48 + (col - 48)] = v;
                    }
            }
        }
    }
}

// combine2: out[r] = log_softmax(mean_nb(y2w) + y2r[r] + b2). 16 rows/block,
// 16 lanes per row (cols c, c+16, c+32). Gathers 96B rows (L2-resident buffer).
__global__ __launch_bounds__(256)
void combine2_kernel(const int* __restrict__ ptr, const int* __restrict__ idx,
                     const unsigned short* __restrict__ y2w,
                     const unsigned short* __restrict__ y2r,
                     const float* __restrict__ b2,
                     float* __restrict__ out)
{
    const int tid = threadIdx.x, lane = tid & 63, wid = tid >> 6;
    const int c = lane & 15, sub = lane >> 4;
    const int row = blockIdx.x * 16 + wid * 4 + sub;
    const int p0 = ptr[row], p1 = ptr[row + 1];
    const float inv = 1.0f / (float)(p1 - p0);
    float s0 = 0.f, s1 = 0.f, s2 = 0.f;
    for (int p = p0; p < p1; ++p) {
        const int nb = idx[p];
        const unsigned short* yr = y2w + (size_t)nb * 48;
        s0 += bf2f(yr[c]); s1 += bf2f(yr[16 + c]); s2 += bf2f(yr[32 + c]);
    }
    const unsigned short* sr = y2r + (size_t)row * 48;
    const bool ok2 = (32 + c) < 47;
    float v0 = s0 * inv + bf2f(sr[c])      + b2[c];
    float v1 = s1 * inv + bf2f(sr[16 + c]) + b2[16 + c];
    float v2 = ok2 ? (s2 * inv + bf2f(sr[32 + c]) + b2[32 + c]) : -3.0e38f;
    float mx = fmaxf(fmaxf(v0, v1), v2);
    #pragma unroll
    for (int o = 1; o < 16; o <<= 1) mx = fmaxf(mx, __shfl_xor(mx, o, 16));
    float s = expf(v0 - mx) + expf(v1 - mx) + (ok2 ? expf(v2 - mx) : 0.f);
    #pragma unroll
    for (int o = 1; o < 16; o <<= 1) s += __shfl_xor(s, o, 16);
    const float ls = mx + logf(s);
    out[(size_t)row * 47 + c]      = v0 - ls;
    out[(size_t)row * 47 + 16 + c] = v1 - ls;
    if (ok2) out[(size_t)row * 47 + 32 + c] = v2 - ls;
}

extern "C" void kernel_launch(void* const* d_in, const int* in_sizes, int n_in,
                              void* d_out, int out_size, void* d_ws, size_t ws_size,
                              hipStream_t stream)
{
    char* ws = (char*)d_ws;
    Args a;
    a.x   = (const float*)d_in[0];
    a.ptr = (const int*)d_in[1];
    a.idx = (const int*)d_in[2];
    a.W0  = (const float*)d_in[3];  a.b0 = (const float*)d_in[4];  a.R0 = (const float*)d_in[5];
    a.W1  = (const float*)d_in[6];  a.b1 = (const float*)d_in[7];  a.R1 = (const float*)d_in[8];
    a.W2  = (const float*)d_in[9];  a.b2 = (const float*)d_in[10]; a.R2 = (const float*)d_in[11];
    a.g0  = (const float*)d_in[12]; a.be0 = (const float*)d_in[13];
    a.rm0 = (const float*)d_in[14]; a.rv0 = (const float*)d_in[15];
    a.g1  = (const float*)d_in[16]; a.be1 = (const float*)d_in[17];
    a.rm1 = (const float*)d_in[18]; a.rv1 = (const float*)d_in[19];
    a.B0  = (unsigned short*)(ws);                        // 128 KB
    a.B1  = (unsigned short*)(ws + 131072);               // 256 KB
    a.Bp2 = (unsigned short*)(ws + 393216);               //  48 KB
    a.xb  = (unsigned short*)(ws + 442368);               // 20000*128 bf16 = 5.12 MB
    a.xb8 = (unsigned char*) (ws + 5562368);              // 20000*128 fp8  = 2.56 MB
    a.h0  = (unsigned short*)(ws + 8122368);              // 20000*256 bf16 = 10.24 MB
    a.h08 = (unsigned char*) (ws + 18362368);             // 20000*256 fp8  = 5.12 MB
    a.y2w = (unsigned short*)(ws + 23482368);             // 20000*48 bf16 = 1.92 MB
    a.y2r = (unsigned short*)(ws + 25402368);             // 20000*48 bf16
    a.out = (float*)d_out;

    prep<<<1280, 256, 0, stream>>>(a);
    layer_kernel<128, false><<<GRID, 256, 0, stream>>>(a.xb, a.xb8, a.ptr, a.idx, a.B0, a.b0,
        a.g0, a.be0, a.rm0, a.rv0, a.h0, a.h08, nullptr, nullptr, nullptr);
    layer_kernel<256, true ><<<GRID, 256, 0, stream>>>(a.h0, a.h08, a.ptr, a.idx, a.B1, a.b1,
        a.g1, a.be1, a.rm1, a.rv1, nullptr, nullptr, a.Bp2, a.y2w, a.y2r);
    combine2_kernel<<<ROWS / 16, 256, 0, stream>>>(a.ptr, a.idx, a.y2w, a.y2r, a.b2, a.out);
}